// Round 5
// baseline (1117.817 us; speedup 1.0000x reference)
//
#include <hip/hip_runtime.h>
#include <math.h>

// Problem constants (from reference)
#define T_TOK 16384
#define DIM   768
#define HID   3072
#define NE    5
#define HCAP  8448          // 33 * 256 row capacity per h buffer
#define CSTR  32            // counts stride (ints) -> one 128B line per expert
#define EPSF  2.2204460492503131e-16f

// grid geometry for combo kernel
#define B2BAND 9            // ceil(65/8)  GEMM2 128-row mt band per XCD
#define B1BAND 5            // ceil(33/8)  GEMM1 256-row mt band per XCD
#define G2BLK  (8 * B2BAND * 3)    // 216
#define G1BLK  (8 * B1BAND * 12)   // 480

typedef short bf16x8  __attribute__((ext_vector_type(8)));   // 8 bf16 in 4 VGPRs
typedef float f32x4   __attribute__((ext_vector_type(4)));
typedef float f32x16  __attribute__((ext_vector_type(16)));

#define MFMA16(A, B, C) __builtin_amdgcn_mfma_f32_16x16x32_bf16((A), (B), (C), 0, 0, 0)
#define MFMA32(A, B, C) __builtin_amdgcn_mfma_f32_32x32x16_bf16((A), (B), (C), 0, 0, 0)

__device__ __forceinline__ unsigned short f2bf(float f) {
    unsigned int u = __float_as_uint(f);
    unsigned int r = (u + 0x7fffu + ((u >> 16) & 1u)) >> 16;  // RNE
    return (unsigned short)r;
}

__device__ __forceinline__ void gld16(const void* g, void* l) {
    __builtin_amdgcn_global_load_lds(
        (const __attribute__((address_space(1))) void*)g,
        (__attribute__((address_space(3))) void*)l, 16, 0, 0);
}

// ---------------- prep: W1 -> 256-col LDS-tile-linear, XOR-swizzled bf16 --------
// chunk c = (e*12 + nb)*12 + kb (16384 elem, 32 KB = one ks-stage of B):
//   W1p[c*16384 + n*64 + p*8 + j] = bf16( W1[e][ kb*64 + (p^(n&7))*8 + j ][ nb*256 + n ] )
__global__ void prep_w1p(const float* __restrict__ W1, unsigned short* __restrict__ W1p) {
    int idx = blockIdx.x * 256 + threadIdx.x;      // NE*12*12*2048 = 1,474,560
    if (idx >= NE * 12 * 12 * 2048) return;
    int pp = idx & 7;
    int n = (idx >> 3) & 255;
    int t = idx >> 11;
    int kb = t % 12; t /= 12;
    int nb = t % 12; int e = t / 12;
    int klog = kb * 64 + (pp ^ (n & 7)) * 8;
    const float* src = W1 + ((size_t)e * DIM + klog) * HID + nb * 256 + n;
    bf16x8 v;
    #pragma unroll
    for (int j = 0; j < 8; ++j) v[j] = (short)f2bf(src[(size_t)j * HID]);
    *reinterpret_cast<bf16x8*>(W1p + (size_t)idx * 8) = v;
}

// chunk c = (e*3 + nb)*48 + kb :
//   W2p[c*16384 + n*64 + p*8 + j] = bf16( W2[e][ kb*64 + (p^(n&7))*8 + j ][ nb*256 + n ] )
__global__ void prep_w2p(const float* __restrict__ W2, unsigned short* __restrict__ W2p) {
    int idx = blockIdx.x * 256 + threadIdx.x;      // NE*3*48*2048 = 1,474,560
    if (idx >= NE * 3 * 48 * 2048) return;
    int pp = idx & 7;
    int n = (idx >> 3) & 255;
    int t = idx >> 11;
    int kb = t % 48; t /= 48;
    int nb = t % 3; int e = t / 3;
    int klog = kb * 64 + (pp ^ (n & 7)) * 8;
    const float* src = W2 + ((size_t)e * HID + klog) * DIM + nb * 256 + n;
    bf16x8 v;
    #pragma unroll
    for (int j = 0; j < 8; ++j) v[j] = (short)f2bf(src[(size_t)j * DIM]);
    *reinterpret_cast<bf16x8*>(W2p + (size_t)idx * 8) = v;
}

// ---------------- gating + x cast, block-aggregated scatter ----------------
__global__ __launch_bounds__(256) void gate_kernel(
    const float* __restrict__ x, const float* __restrict__ wg,
    unsigned short* __restrict__ xb, int* __restrict__ counts,
    int* __restrict__ btok, float* __restrict__ bgate) {
    __shared__ int   s_e[2][64];
    __shared__ float s_g[2][64];
    __shared__ int   lcnt[NE];
    __shared__ int   gbase[NE];

    const int tid = threadIdx.x;
    if (tid < NE) lcnt[tid] = 0;
    const int grp = tid >> 4, l16 = tid & 15;
    const int t0 = blockIdx.x * 64 + grp * 4;

    double acc[4][NE];
    #pragma unroll
    for (int tt = 0; tt < 4; ++tt)
        #pragma unroll
        for (int e = 0; e < NE; ++e) acc[tt][e] = 0.0;

    for (int i = 0; i < 12; ++i) {
        const int dbase = i * 64 + l16 * 4;
        float4 xv[4];
        #pragma unroll
        for (int tt = 0; tt < 4; ++tt) {
            xv[tt] = *reinterpret_cast<const float4*>(x + (size_t)(t0 + tt) * DIM + dbase);
            ushort4 o;
            o.x = f2bf(xv[tt].x); o.y = f2bf(xv[tt].y);
            o.z = f2bf(xv[tt].z); o.w = f2bf(xv[tt].w);
            *reinterpret_cast<ushort4*>(xb + (size_t)(t0 + tt) * DIM + dbase) = o;
        }
        #pragma unroll
        for (int j = 0; j < 4; ++j) {
            const int d = dbase + j;
            float w0 = wg[d * NE + 0], w1 = wg[d * NE + 1], w2 = wg[d * NE + 2];
            float w3 = wg[d * NE + 3], w4 = wg[d * NE + 4];
            #pragma unroll
            for (int tt = 0; tt < 4; ++tt) {
                double xd = (double)((&xv[tt].x)[j]);
                acc[tt][0] += xd * (double)w0;
                acc[tt][1] += xd * (double)w1;
                acc[tt][2] += xd * (double)w2;
                acc[tt][3] += xd * (double)w3;
                acc[tt][4] += xd * (double)w4;
            }
        }
    }
    #pragma unroll
    for (int off = 8; off; off >>= 1)
        #pragma unroll
        for (int tt = 0; tt < 4; ++tt)
            #pragma unroll
            for (int e = 0; e < NE; ++e)
                acc[tt][e] += __shfl_down(acc[tt][e], off, 16);

    if (l16 == 0) {
        #pragma unroll
        for (int tt = 0; tt < 4; ++tt) {
            double v[NE] = {acc[tt][0], acc[tt][1], acc[tt][2], acc[tt][3], acc[tt][4]};
            int i0 = 0;
            for (int e = 1; e < NE; ++e) if (v[e] > v[i0]) i0 = e;
            int i1 = -1;
            for (int e = 0; e < NE; ++e) {
                if (e == i0) continue;
                if (i1 < 0 || v[e] > v[i1]) i1 = e;
            }
            float e1 = expf((float)(v[i1] - v[i0]));
            float g0 = 1.0f / (1.0f + e1);
            int li = grp * 4 + tt;
            s_e[0][li] = i0;  s_g[0][li] = g0;
            s_e[1][li] = i1;  s_g[1][li] = e1 * g0;
        }
    }
    __syncthreads();

    int mye = 0, myoff = 0, mytok = 0;
    float myg = 0.0f;
    if (tid < 128) {
        int li = tid >> 1, which = tid & 1;
        mye = s_e[which][li];
        myg = s_g[which][li];
        mytok = blockIdx.x * 64 + li;
        myoff = atomicAdd(&lcnt[mye], 1);
    }
    __syncthreads();
    if (tid < NE) gbase[tid] = atomicAdd(&counts[tid * CSTR], lcnt[tid]);
    __syncthreads();
    if (tid < 128) {
        int p = gbase[mye] + myoff;
        btok[mye * T_TOK + p] = mytok;
        bgate[mye * T_TOK + p] = myg;
    }
}

// ---------------- combo GEMM kernel v5 ----------------
// 512 threads (8 waves), LDS double-buffered, ONE barrier per ks.
// GEMM2 region (blocks [0,216)): expert g2e, 128x256 tile, K=3072 (48 ks).
//   waves 2x4, wave tile 64x64 (acc 4x4).
// GEMM1 region (blocks [216, 216+480)): expert g1e, 256x256 tile, K=768 (12 ks).
//   waves 4x2, wave tile 64x128 (acc 4x8).
// XCD-aware mapping: xcd = bx&7, mt-band inner -> A band + B tile stay in
// per-XCD L2. B is pre-swizzled to LDS-linear 16 KB/32 KB ks-chunks.
__global__ __launch_bounds__(512, 2) void combo_kernel(
    const unsigned short* __restrict__ xb,
    const unsigned short* __restrict__ W1p,
    const unsigned short* __restrict__ W2p,
    const float* __restrict__ b1, const float* __restrict__ b2,
    const int* __restrict__ counts, const int* __restrict__ btok,
    const float* __restrict__ bgate,
    unsigned short* __restrict__ h0, unsigned short* __restrict__ h1,
    float* __restrict__ out, int g1e, int g2e) {
    __shared__ __align__(16) unsigned short smem[65536];   // 128 KB
    __shared__ int   sst[128];
    __shared__ float ssg[128];

    const int g2n = (g2e >= 0) ? G2BLK : 0;
    const int tid = threadIdx.x;
    const int wv = tid >> 6, lane = tid & 63;
    const int col16 = lane & 15, quad = lane >> 4;
    const int l8 = lane & 7;
    const int r8 = (tid >> 3) & 7;

    if (blockIdx.x < g2n) {
        // ======================= GEMM2: h @ W2 -> out =======================
        const int e = g2e;
        const int xcd = blockIdx.x & 7, i = blockIdx.x >> 3;
        const int nt = i / B2BAND, mtl = i % B2BAND;   // nt-outer, mt-band inner
        const int mt = xcd * B2BAND + mtl;
        const int cnt = counts[e * CSTR];
        const int m0 = mt * 128;
        if (m0 >= cnt) return;
        const unsigned short* hbuf = (e & 1) ? h1 : h0;

        if (tid < 128) {
            int pos = m0 + tid;
            sst[tid] = (pos < cnt) ? btok[e * T_TOK + pos] : 0;
            ssg[tid] = (pos < cnt) ? bgate[e * T_TOK + pos] : 0.0f;
        }
        // A: 128x64 per ks (2 slots), B: 256x64 (4 slots)
        const unsigned short* ap0 =
            hbuf + (size_t)(m0 + (tid >> 3)) * HID + (l8 ^ r8) * 8;
        const unsigned short* ap1 =
            hbuf + (size_t)(m0 + 64 + (tid >> 3)) * HID + (l8 ^ r8) * 8;
        const unsigned short* btile = W2p + (size_t)((e * 3 + nt) * 48) * 16384;

        f32x4 acc[4][4];
        #pragma unroll
        for (int a_ = 0; a_ < 4; ++a_)
            #pragma unroll
            for (int b_ = 0; b_ < 4; ++b_)
                acc[a_][b_] = (f32x4){0.f, 0.f, 0.f, 0.f};

        const int wm = wv >> 2, wn = wv & 3;
        // prologue stage ks=0 into buffer 0
        {
            gld16(ap0, smem + wv * 512);
            gld16(ap1, smem + (8 + wv) * 512);
            const unsigned short* bsrc = btile + wv * 512 + lane * 8;
            #pragma unroll
            for (int q = 0; q < 4; ++q)
                gld16(bsrc + q * 4096, smem + 16384 + (q * 8 + wv) * 512);
        }
        int p = 0;
        for (int ks = 0; ks < 48; ++ks) {
            __syncthreads();   // buf[p] DMA complete; prior reads of buf[p^1] done
            if (ks + 1 < 48) {
                const int pn = p ^ 1;
                const int kn = ks + 1;
                gld16(ap0 + kn * 64, smem + pn * 8192 + wv * 512);
                gld16(ap1 + kn * 64, smem + pn * 8192 + (8 + wv) * 512);
                const unsigned short* bsrc = btile + kn * 16384 + wv * 512 + lane * 8;
                #pragma unroll
                for (int q = 0; q < 4; ++q)
                    gld16(bsrc + q * 4096, smem + 16384 + pn * 16384 + (q * 8 + wv) * 512);
            }
            const unsigned short* Ab = smem + p * 8192;
            const unsigned short* Bb = smem + 16384 + p * 16384;
            #pragma unroll
            for (int kf = 0; kf < 2; ++kf) {
                const int pa = ((kf * 4 + quad) ^ l8) * 8;
                bf16x8 a[4], b[4];
                #pragma unroll
                for (int ii = 0; ii < 4; ++ii)
                    a[ii] = *reinterpret_cast<const bf16x8*>(
                        &Ab[(wm * 64 + ii * 16 + col16) * 64 + pa]);
                #pragma unroll
                for (int jj = 0; jj < 4; ++jj)
                    b[jj] = *reinterpret_cast<const bf16x8*>(
                        &Bb[(wn * 64 + jj * 16 + col16) * 64 + pa]);
                #pragma unroll
                for (int ii = 0; ii < 4; ++ii)
                    #pragma unroll
                    for (int jj = 0; jj < 4; ++jj)
                        acc[ii][jj] = MFMA16(a[ii], b[jj], acc[ii][jj]);
            }
            p ^= 1;
        }
        // epilogue: out[t] += g * exp(acc + b2)
        const int nb0 = nt * 256 + wn * 64;
        #pragma unroll
        for (int jj = 0; jj < 4; ++jj) {
            float bias = b2[e * DIM + nb0 + jj * 16 + col16];
            #pragma unroll
            for (int ii = 0; ii < 4; ++ii) {
                #pragma unroll
                for (int r = 0; r < 4; ++r) {
                    int lrow = wm * 64 + ii * 16 + quad * 4 + r;
                    float g = ssg[lrow];
                    if (g > 0.0f) {
                        float v = acc[ii][jj][r] + bias;
                        atomicAdd(out + (size_t)sst[lrow] * DIM + nb0 + jj * 16 + col16,
                                  g * expf(v));
                    }
                }
            }
        }
    } else {
        // ======================= GEMM1: x @ W1 -> h =======================
        const int e = g1e;
        const int bxr = blockIdx.x - g2n;
        const int xcd = bxr & 7, i = bxr >> 3;
        const int nt = i / B1BAND, mtl = i % B1BAND;   // nt-outer, mt-band inner
        const int mt = xcd * B1BAND + mtl;
        const int cnt = counts[e * CSTR];
        const int m0 = mt * 256;
        if (m0 >= cnt) return;
        unsigned short* hbuf = (e & 1) ? h1 : h0;

        // A: 256x64 per ks (4 slots, gathered token rows)
        const unsigned short* aptr[4];
        #pragma unroll
        for (int q = 0; q < 4; ++q) {
            int row = q * 64 + (tid >> 3);
            int pos = m0 + row;
            int tok = btok[e * T_TOK + (pos < cnt ? pos : 0)];
            aptr[q] = xb + (size_t)tok * DIM + (l8 ^ r8) * 8;
        }
        const unsigned short* btile = W1p + (size_t)((e * 12 + nt) * 12) * 16384;

        f32x4 acc[4][8];
        #pragma unroll
        for (int a_ = 0; a_ < 4; ++a_)
            #pragma unroll
            for (int b_ = 0; b_ < 8; ++b_)
                acc[a_][b_] = (f32x4){0.f, 0.f, 0.f, 0.f};

        const int wm = wv >> 1, wn = wv & 1;
        // prologue stage ks=0 into buffer 0
        {
            #pragma unroll
            for (int q = 0; q < 4; ++q)
                gld16(aptr[q], smem + (q * 8 + wv) * 512);
            const unsigned short* bsrc = btile + wv * 512 + lane * 8;
            #pragma unroll
            for (int q = 0; q < 4; ++q)
                gld16(bsrc + q * 4096, smem + 32768 + (q * 8 + wv) * 512);
        }
        int p = 0;
        for (int ks = 0; ks < 12; ++ks) {
            __syncthreads();
            if (ks + 1 < 12) {
                const int pn = p ^ 1;
                const int kn = ks + 1;
                #pragma unroll
                for (int q = 0; q < 4; ++q)
                    gld16(aptr[q] + kn * 64, smem + pn * 16384 + (q * 8 + wv) * 512);
                const unsigned short* bsrc = btile + kn * 16384 + wv * 512 + lane * 8;
                #pragma unroll
                for (int q = 0; q < 4; ++q)
                    gld16(bsrc + q * 4096, smem + 32768 + pn * 16384 + (q * 8 + wv) * 512);
            }
            const unsigned short* Ab = smem + p * 16384;
            const unsigned short* Bb = smem + 32768 + p * 16384;
            #pragma unroll
            for (int kf = 0; kf < 2; ++kf) {
                const int pa = ((kf * 4 + quad) ^ l8) * 8;
                bf16x8 a[4], b[8];
                #pragma unroll
                for (int ii = 0; ii < 4; ++ii)
                    a[ii] = *reinterpret_cast<const bf16x8*>(
                        &Ab[(wm * 64 + ii * 16 + col16) * 64 + pa]);
                #pragma unroll
                for (int jj = 0; jj < 8; ++jj)
                    b[jj] = *reinterpret_cast<const bf16x8*>(
                        &Bb[(wn * 128 + jj * 16 + col16) * 64 + pa]);
                #pragma unroll
                for (int ii = 0; ii < 4; ++ii)
                    #pragma unroll
                    for (int jj = 0; jj < 8; ++jj)
                        acc[ii][jj] = MFMA16(a[ii], b[jj], acc[ii][jj]);
            }
            p ^= 1;
        }
        // epilogue: h = gelu(acc + b1)
        const int nb0 = nt * 256 + wn * 128;
        #pragma unroll
        for (int jj = 0; jj < 8; ++jj) {
            float bias = b1[e * HID + nb0 + jj * 16 + col16];
            #pragma unroll
            for (int ii = 0; ii < 4; ++ii) {
                #pragma unroll
                for (int r = 0; r < 4; ++r) {
                    int row = m0 + wm * 64 + ii * 16 + quad * 4 + r;
                    float v = acc[ii][jj][r] + bias;
                    float gl = 0.5f * v * (1.0f + erff(v * 0.70710678118654752f));
                    hbuf[(size_t)row * HID + nb0 + jj * 16 + col16] = f2bf(gl);
                }
            }
        }
    }
}

// ---------------- final: out = log(acc), eps guard ----------------
__global__ void log_kernel(float* __restrict__ out, int n) {
    int i = blockIdx.x * 256 + threadIdx.x;
    if (i < n) {
        float v = out[i];
        out[i] = logf(v == 0.0f ? EPSF : v);
    }
}

// ================= round-2 fallback path (used only if ws too small) =================
__global__ void prep_w1_v2(const float* __restrict__ W1, unsigned short* __restrict__ W1s) {
    int g = blockIdx.x * 4 + (threadIdx.x >> 6);
    int lane = threadIdx.x & 63;
    int kf = g % 48;
    int rest = g / 48;
    int nt2 = rest % 96;
    int e = rest / 96;
    int n = nt2 * 32 + (lane & 31);
    int k0 = kf * 16 + (lane >> 5) * 8;
    const float* src = W1 + ((size_t)e * DIM + k0) * HID + n;
    bf16x8 v;
    #pragma unroll
    for (int j = 0; j < 8; ++j) v[j] = (short)f2bf(src[(size_t)j * HID]);
    *reinterpret_cast<bf16x8*>(W1s + ((size_t)g * 64 + lane) * 8) = v;
}

__global__ void prep_w2_v2(const float* __restrict__ W2, unsigned short* __restrict__ W2s) {
    int g = blockIdx.x * 4 + (threadIdx.x >> 6);
    int lane = threadIdx.x & 63;
    int kf = g % 192;
    int rest = g / 192;
    int nt2 = rest % 24;
    int e = rest / 24;
    int n = nt2 * 32 + (lane & 31);
    int k0 = kf * 16 + (lane >> 5) * 8;
    const float* src = W2 + ((size_t)e * HID + k0) * DIM + n;
    bf16x8 v;
    #pragma unroll
    for (int j = 0; j < 8; ++j) v[j] = (short)f2bf(src[(size_t)j * DIM]);
    *reinterpret_cast<bf16x8*>(W2s + ((size_t)g * 64 + lane) * 8) = v;
}

__global__ __launch_bounds__(512, 2) void expert_v2(
    const unsigned short* __restrict__ xb, const unsigned short* __restrict__ W1s,
    const unsigned short* __restrict__ W2s, const float* __restrict__ b1,
    const float* __restrict__ b2, const int* __restrict__ counts,
    const int* __restrict__ btok, const float* __restrict__ bgate,
    float* __restrict__ out) {
    __shared__ __align__(16) unsigned short xs[64][776];
    __shared__ __align__(16) unsigned short hs[2][64][136];
    __shared__ int   st[64];
    __shared__ float sg[64];

    const int e = blockIdx.y;
    const int cnt = counts[e * CSTR];
    const int m0 = blockIdx.x * 64;
    if (m0 >= cnt) return;

    const int tid = threadIdx.x;
    const int wv = tid >> 6, lane = tid & 63;
    const int l31 = lane & 31, lhi = lane >> 5;

    if (tid < 64) {
        int pos = m0 + tid;
        st[tid] = (pos < cnt) ? btok[e * T_TOK + pos] : 0;
        sg[tid] = (pos < cnt) ? bgate[e * T_TOK + pos] : 0.0f;
    }
    __syncthreads();
    {
        int r = tid >> 3, seg = tid & 7;
        const unsigned short* src = xb + (size_t)st[r] * DIM + seg * 96;
        unsigned short* dst = &xs[r][seg * 96];
        #pragma unroll
        for (int i = 0; i < 12; ++i)
            reinterpret_cast<bf16x8*>(dst)[i] = reinterpret_cast<const bf16x8*>(src)[i];
    }
    __syncthreads();

    const int mt2 = wv & 1, nt2l = wv >> 1;
    f32x16 acc[2][3];
    #pragma unroll
    for (int a_ = 0; a_ < 2; ++a_)
        #pragma unroll
        for (int b_ = 0; b_ < 3; ++b_)
            #pragma unroll
            for (int q = 0; q < 16; ++q) acc[a_][b_][q] = 0.0f;

    const unsigned short* arow = &xs[mt2 * 32 + l31][lhi * 8];
    for (int jc = 0; jc < 24; ++jc) {
        f32x16 c0, c1;
        #pragma unroll
        for (int q = 0; q < 16; ++q) { c0[q] = 0.0f; c1[q] = 0.0f; }
        const unsigned short* bpa =
            W1s + ((size_t)((e * 96 + jc * 4 + nt2l) * 48)) * 512 + lane * 8;
        #pragma unroll
        for (int kf = 0; kf < 48; kf += 2) {
            bf16x8 a0 = *reinterpret_cast<const bf16x8*>(arow + kf * 16);
            bf16x8 b0 = *reinterpret_cast<const bf16x8*>(bpa + (size_t)kf * 512);
            c0 = MFMA32(a0, b0, c0);
            bf16x8 a1 = *reinterpret_cast<const bf16x8*>(arow + kf * 16 + 16);
            bf16x8 b1 = *reinterpret_cast<const bf16x8*>(bpa + (size_t)kf * 512 + 512);
            c1 = MFMA32(a1, b1, c1);
        }
        #pragma unroll
        for (int q = 0; q < 16; ++q) c0[q] += c1[q];
        {
            int colc = nt2l * 32 + l31;
            float bias = b1[e * HID + jc * 128 + colc];
            #pragma unroll
            for (int reg = 0; reg < 16; ++reg) {
                int row = (reg & 3) + 8 * (reg >> 2) + 4 * lhi;
                float v = c0[reg] + bias;
                float gl = 0.5f * v * (1.0f + erff(v * 0.70710678118654752f));
                hs[jc & 1][mt2 * 32 + row][colc] = f2bf(gl);
            }
        }
        __syncthreads();
        const unsigned short* bpb =
            W2s + ((size_t)((e * 24 + wv * 3) * 192 + jc * 8)) * 512 + lane * 8;
        #pragma unroll
        for (int kf = 0; kf < 8; ++kf) {
            bf16x8 af0 = *reinterpret_cast<const bf16x8*>(&hs[jc & 1][l31][kf * 16 + lhi * 8]);
            bf16x8 af1 = *reinterpret_cast<const bf16x8*>(&hs[jc & 1][32 + l31][kf * 16 + lhi * 8]);
            #pragma unroll
            for (int i = 0; i < 3; ++i) {
                bf16x8 bv = *reinterpret_cast<const bf16x8*>(bpb + ((size_t)i * 192 + kf) * 512);
                acc[0][i] = MFMA32(af0, bv, acc[0][i]);
                acc[1][i] = MFMA32(af1, bv, acc[1][i]);
            }
        }
    }
    #pragma unroll
    for (int mt = 0; mt < 2; ++mt) {
        #pragma unroll
        for (int i = 0; i < 3; ++i) {
            int cg = (wv * 3 + i) * 32 + l31;
            float bias2 = b2[e * DIM + cg];
            #pragma unroll
            for (int reg = 0; reg < 16; ++reg) {
                int row = mt * 32 + (reg & 3) + 8 * (reg >> 2) + 4 * lhi;
                float g = sg[row];
                if (g > 0.0f) {
                    float v = acc[mt][i][reg] + bias2;
                    atomicAdd(out + (size_t)st[row] * DIM + cg, g * expf(v));
                }
            }
        }
    }
}

// =====================================================================

extern "C" void kernel_launch(void* const* d_in, const int* in_sizes, int n_in,
                              void* d_out, int out_size, void* d_ws, size_t ws_size,
                              hipStream_t stream) {
    const float* x  = (const float*)d_in[0];
    const float* wg = (const float*)d_in[1];
    const float* W1 = (const float*)d_in[2];
    const float* b1 = (const float*)d_in[3];
    const float* W2 = (const float*)d_in[4];
    const float* b2 = (const float*)d_in[5];
    float* out = (float*)d_out;

    // workspace layout (~177 MB)
    char* ws = (char*)d_ws;
    int*            counts = (int*)ws;                                   // 5*128B padded
    int*            btok   = (int*)(ws + 1024);                          // 320 KB
    float*          bgate  = (float*)(ws + 1024 + 327680);               // 320 KB
    unsigned short* xb     = (unsigned short*)(ws + 1024 + 2 * 327680);  // 24 MB
    unsigned short* W1b    = xb + (size_t)T_TOK * DIM;                   // 22.5 MB
    unsigned short* W2b    = W1b + (size_t)NE * DIM * HID;               // 22.5 MB
    unsigned short* h0     = W2b + (size_t)NE * HID * DIM;               // 49.5 MB
    unsigned short* h1     = h0 + (size_t)HCAP * HID;                    // 49.5 MB

    const size_t need_fast = 1024 + 2 * 327680
        + (size_t)T_TOK * DIM * 2 + 2 * (size_t)NE * DIM * HID * 2
        + 2 * (size_t)HCAP * HID * 2;
    const bool fast = ws_size >= need_fast;

    hipMemsetAsync(counts, 0, 1024, stream);
    hipMemsetAsync(out, 0, (size_t)out_size * sizeof(float), stream);

    gate_kernel<<<T_TOK / 64, 256, 0, stream>>>(x, wg, xb, counts, btok, bgate);

    if (fast) {
        prep_w1p<<<(NE * 12 * 12 * 2048 + 255) / 256, 256, 0, stream>>>(W1, W1b);
        prep_w2p<<<(NE * 3 * 48 * 2048 + 255) / 256, 256, 0, stream>>>(W2, W2b);
        for (int s = 0; s < 6; ++s) {
            int g1e = (s <= 4) ? s : -1;
            int g2e = s - 1;
            int nb = (g2e >= 0 ? G2BLK : 0) + (g1e >= 0 ? G1BLK : 0);
            combo_kernel<<<nb, 512, 0, stream>>>(xb, W1b, W2b, b1, b2, counts,
                                                 btok, bgate, h0, h1, out, g1e, g2e);
        }
    } else {
        prep_w1_v2<<<NE * 96 * 48 / 4, 256, 0, stream>>>(W1, W1b);
        prep_w2_v2<<<NE * 24 * 192 / 4, 256, 0, stream>>>(W2, W2b);
        expert_v2<<<dim3(T_TOK / 64, NE), 512, 0, stream>>>(
            xb, W1b, W2b, b1, b2, counts, btok, bgate, out);
    }

    log_kernel<<<(out_size + 255) / 256, 256, 0, stream>>>(out, out_size);
}